// Round 10
// baseline (255.737 us; speedup 1.0000x reference)
//
#include <hip/hip_runtime.h>

#define B_   16
#define C_   64
#define HW_  65536
#define CHW_ (C_ * HW_)   // 4194304 elements per batch

typedef short bf16x8 __attribute__((ext_vector_type(8)));
typedef float f32x4v __attribute__((ext_vector_type(4)));

// fp32 -> bf16 round-to-nearest-even
__device__ __forceinline__ unsigned short bfrne(float f) {
    unsigned int u = __float_as_uint(f);
    u += 0x7FFFu + ((u >> 16) & 1u);
    return (unsigned short)(u >> 16);
}
__device__ __forceinline__ float bfdec(unsigned short h) {
    return __uint_as_float((unsigned int)h << 16);
}

// ---------------------------------------------------------------------------
// Kernel 1 v5 (split-bf16 MFMA, slim 32x64 wave tiles for 16 waves/CU):
// S[b,c,d] = sum_n A[c][n]*B[n][d];  x = hi+lo bf16, S ~= hh+hl+lh.
// Wave (ctg = w>>1, nh = w&1): c-rows [32ctg, 32ctg+32), n-half nh.
// The two ctg-twin waves read the same B bytes concurrently (L1 hit).
// Epilogue: 2-phase LDS reduce over n-halves.
// ---------------------------------------------------------------------------
__global__ __launch_bounds__(256, 3) void k1_gram(const float* __restrict__ x,
                                                  float* __restrict__ partial,
                                                  int nch, int nb) {
    const int ch  = blockIdx.x;
    const int b   = blockIdx.y;
    const int t   = threadIdx.x;
    const int w   = t >> 6;
    const int l   = t & 63;
    const int g   = l >> 4;      // k-octet selector
    const int col = l & 15;      // A-row / B-col within 16-tile
    const int ctg = w >> 1;      // c-group (rows 32*ctg ..)
    const int nh  = w & 1;       // n-half

    const float* xb = x + (size_t)b * CHW_;
    const int nq  = nb >> 1;     // n per wave
    const int nw0 = ch * nb + nh * nq;

    f32x4v acc[2][4];            // [ct2][dt]
    #pragma unroll
    for (int ct = 0; ct < 2; ct++)
        #pragma unroll
        for (int dt = 0; dt < 4; dt++) acc[ct][dt] = (f32x4v)(0.f);

    for (int ns = nw0; ns < nw0 + nq; ns += 32) {
        // --- A fragments: lane holds A[32ctg+16ct2+col][ns+8g+j] ---
        bf16x8 ahi[2], alo[2];
        #pragma unroll
        for (int ct = 0; ct < 2; ct++) {
            const float* ap = xb + (size_t)(32 * ctg + 16 * ct + col) * HW_ + ns + 8 * g;
            float av[8];
            *(float4*)&av[0] = *(const float4*)ap;
            *(float4*)&av[4] = *(const float4*)(ap + 4);
            #pragma unroll
            for (int j = 0; j < 8; j++) {
                const unsigned short h = bfrne(av[j]);
                ahi[ct][j] = (short)h;
                alo[ct][j] = (short)bfrne(av[j] - bfdec(h));
            }
        }
        // --- B fragments: lane holds B[ns+8g+j][16dt+col] ---
        bf16x8 bhi[4], blo[4];
        #pragma unroll
        for (int dt = 0; dt < 4; dt++) {
            const float* bp = xb + (size_t)(ns + 8 * g) * C_ + 16 * dt + col;
            float bv[8];
            #pragma unroll
            for (int j = 0; j < 8; j++) bv[j] = bp[j * C_];
            #pragma unroll
            for (int j = 0; j < 8; j++) {
                const unsigned short h = bfrne(bv[j]);
                bhi[dt][j] = (short)h;
                blo[dt][j] = (short)bfrne(bv[j] - bfdec(h));
            }
        }
        // --- 24 MFMAs: hi*hi + hi*lo + lo*hi ---
        #pragma unroll
        for (int ct = 0; ct < 2; ct++)
            #pragma unroll
            for (int dt = 0; dt < 4; dt++) {
                acc[ct][dt] = __builtin_amdgcn_mfma_f32_16x16x32_bf16(
                    ahi[ct], bhi[dt], acc[ct][dt], 0, 0, 0);
                acc[ct][dt] = __builtin_amdgcn_mfma_f32_16x16x32_bf16(
                    ahi[ct], blo[dt], acc[ct][dt], 0, 0, 0);
                acc[ct][dt] = __builtin_amdgcn_mfma_f32_16x16x32_bf16(
                    alo[ct], bhi[dt], acc[ct][dt], 0, 0, 0);
            }
    }

    // --- cross-wave reduce over n-halves: D[32ctg+16ct2+4g+r][16dt+col] ---
    __shared__ float sred[4096];
    for (int wr = 0; wr < 2; wr++) {
        if (nh == wr) {
            #pragma unroll
            for (int ct = 0; ct < 2; ct++)
                #pragma unroll
                for (int dt = 0; dt < 4; dt++)
                    #pragma unroll
                    for (int r = 0; r < 4; r++) {
                        const int idx = (32 * ctg + 16 * ct + 4 * g + r) * 64
                                        + 16 * dt + col;
                        if (wr == 0) sred[idx] = acc[ct][dt][r];
                        else         sred[idx] += acc[ct][dt][r];
                    }
        }
        __syncthreads();
    }

    float* pb = partial + (size_t)(b * nch + ch) * 4096;
    for (int i = 4 * t; i < 4096; i += 1024)
        *(float4*)&pb[i] = *(const float4*)&sred[i];
}

// ---------------------------------------------------------------------------
// Kernel 2 v3: reduce partials + softmax (unchanged).
// Writes mbf[b,c,d] = bf16( softmax(S)[b,c,d] + (c==d) ).
// ---------------------------------------------------------------------------
__global__ __launch_bounds__(256) void k2_softmax(const float* __restrict__ partial,
                                                  unsigned short* __restrict__ mbf,
                                                  int nch) {
    const int c = blockIdx.x;
    const int b = blockIdx.y;
    const int t = threadIdx.x;
    const int w = t >> 6;
    const int d = t & 63;

    float s = 0.f;
    for (int ch = w; ch < nch; ch += 4)
        s += partial[(size_t)(b * nch + ch) * 4096 + c * 64 + d];

    __shared__ float red[256];
    red[t] = s;
    __syncthreads();
    if (w == 0) {
        s = red[d] + red[64 + d] + red[128 + d] + red[192 + d];
        float m = s;
        #pragma unroll
        for (int off = 32; off > 0; off >>= 1) m = fmaxf(m, __shfl_xor(m, off));
        const float e = expf(s - m);
        float sum = e;
        #pragma unroll
        for (int off = 32; off > 0; off >>= 1) sum += __shfl_xor(sum, off);
        mbf[(size_t)b * 4096 + c * 64 + d] = bfrne(e / sum + (c == d ? 1.f : 0.f));
    }
}

// ---------------------------------------------------------------------------
// Kernel 3 v7 (MFMA bf16, slim 32x64 wave tiles + ping-pong load pairs):
// out[b,c,n] = sum_d M[c,d] * X[b, d*HW + n]
// Wave (ctg = w>>1, nw = w&1): c-rows [32ctg,32ctg+32), n-window
// [nbk*128 + 64*nw, +64).  ctg-twin waves share x bytes (L1 hit).
// x loads: two 16-float buffers ping-pong so 16 loads are in flight
// while the previous pair converts + MFMAs.
// ---------------------------------------------------------------------------
__global__ __launch_bounds__(256, 3) void k3_out(const float* __restrict__ x,
                                                 const unsigned short* __restrict__ mbf,
                                                 float* __restrict__ out) {
    const int nbk  = blockIdx.x;
    const int b    = blockIdx.y;
    const int t    = threadIdx.x;
    const int w    = t >> 6;
    const int l    = t & 63;
    const int g    = l >> 4;
    const int col  = l & 15;
    const int ctg  = w >> 1;
    const int nw   = w & 1;

    const int n0 = nbk * 128 + nw * 64;
    const float* xb = x + (size_t)b * CHW_;

    // --- A-fragments: M rows 32ctg+16ct2+col ---
    bf16x8 afr[2][2];
    const unsigned short* mb = mbf + (size_t)b * 4096;
    #pragma unroll
    for (int ct = 0; ct < 2; ct++)
        #pragma unroll
        for (int ks = 0; ks < 2; ks++)
            afr[ct][ks] = *(const bf16x8*)(mb + (32 * ctg + 16 * ct + col) * 64
                                           + 32 * ks + 8 * g);

    f32x4v acc[2][4];   // [ct2][nt]
    #pragma unroll
    for (int ct = 0; ct < 2; ct++)
        #pragma unroll
        for (int nt = 0; nt < 4; nt++)
            acc[ct][nt] = (f32x4v)(0.f);

#define K3_LOADF(P, nt)                                                    \
    {                                                                      \
        const float* xpf = xb + n0 + 16 * (nt) + col;                      \
        _Pragma("unroll")                                                  \
        for (int ks = 0; ks < 2; ks++)                                     \
            _Pragma("unroll")                                              \
            for (int j = 0; j < 8; j++)                                    \
                P[8 * ks + j] = xpf[(size_t)(32 * ks + 8 * g + j) * HW_];  \
    }

#define K3_CONV(BF, P)                                                     \
    _Pragma("unroll")                                                      \
    for (int ks = 0; ks < 2; ks++)                                         \
        _Pragma("unroll")                                                  \
        for (int j = 0; j < 8; j++)                                        \
            BF[ks][j] = (short)bfrne(P[8 * ks + j]);

#define K3_MFMA(BF, nt)                                                    \
    _Pragma("unroll")                                                      \
    for (int ct = 0; ct < 2; ct++)                                         \
        _Pragma("unroll")                                                  \
        for (int ks = 0; ks < 2; ks++)                                     \
            acc[ct][nt] = __builtin_amdgcn_mfma_f32_16x16x32_bf16(         \
                afr[ct][ks], BF[ks], acc[ct][nt], 0, 0, 0);

    float pA[16], pB[16];
    bf16x8 bfA[2], bfB[2];

    K3_LOADF(pA, 0);
    K3_LOADF(pB, 1);

    K3_CONV(bfA, pA);
    K3_LOADF(pA, 2);          // in flight during MFMA(nt=0)
    K3_MFMA(bfA, 0);

    K3_CONV(bfB, pB);
    K3_LOADF(pB, 3);          // in flight during MFMA(nt=1)
    K3_MFMA(bfB, 1);

    K3_CONV(bfA, pA);
    K3_MFMA(bfA, 2);

    K3_CONV(bfB, pB);
    K3_MFMA(bfB, 3);

#undef K3_LOADF
#undef K3_CONV
#undef K3_MFMA

    // --- store: D[row=32ctg+16ct2+4g+r][col=n0+16nt+col] ---
    float* ob = out + (size_t)b * CHW_;
    #pragma unroll
    for (int ct = 0; ct < 2; ct++)
        #pragma unroll
        for (int nt = 0; nt < 4; nt++)
            #pragma unroll
            for (int r = 0; r < 4; r++)
                ob[(size_t)(32 * ctg + 16 * ct + 4 * g + r) * HW_ + n0 + 16 * nt + col] =
                    acc[ct][nt][r];
}

// ---------------------------------------------------------------------------
extern "C" void kernel_launch(void* const* d_in, const int* in_sizes, int n_in,
                              void* d_out, int out_size, void* d_ws, size_t ws_size,
                              hipStream_t stream) {
    const float* x = (const float*)d_in[0];
    float* out = (float*)d_out;

    float* wsf          = (float*)d_ws;
    unsigned short* mbf = (unsigned short*)wsf;      // B*4096 ushorts (128KB)
    float* partial      = wsf + (size_t)B_ * 4096;   // B*nch*4096 floats

    int nch = 64;
    while (nch > 1) {
        size_t need = (size_t)B_ * 4096 * sizeof(float)
                    + (size_t)B_ * nch * 4096 * sizeof(float);
        if (need <= ws_size) break;
        nch >>= 1;
    }
    const int nb = HW_ / nch;

    k1_gram<<<dim3(nch, B_), 256, 0, stream>>>(x, partial, nch, nb);
    k2_softmax<<<dim3(C_, B_), 256, 0, stream>>>(partial, mbf, nch);
    k3_out<<<dim3(HW_ / 128, B_), 256, 0, stream>>>(x, mbf, out);
}

// Round 11
// 231.829 us; speedup vs baseline: 1.1031x; 1.1031x over previous
//
#include <hip/hip_runtime.h>

#define B_   16
#define C_   64
#define HW_  65536
#define CHW_ (C_ * HW_)   // 4194304 elements per batch

typedef short bf16x8 __attribute__((ext_vector_type(8)));
typedef float f32x4v __attribute__((ext_vector_type(4)));

// fp32 -> bf16 round-to-nearest-even
__device__ __forceinline__ unsigned short bfrne(float f) {
    unsigned int u = __float_as_uint(f);
    u += 0x7FFFu + ((u >> 16) & 1u);
    return (unsigned short)(u >> 16);
}
__device__ __forceinline__ float bfdec(unsigned short h) {
    return __uint_as_float((unsigned int)h << 16);
}

// ---------------------------------------------------------------------------
// Kernel 1 v5 (split-bf16 MFMA, slim 32x64 wave tiles — kept from R10 for
// attribution): S[b,c,d] = sum_n A[c][n]*B[n][d]; S ~= hh+hl+lh.
// ---------------------------------------------------------------------------
__global__ __launch_bounds__(256, 3) void k1_gram(const float* __restrict__ x,
                                                  float* __restrict__ partial,
                                                  int nch, int nb) {
    const int ch  = blockIdx.x;
    const int b   = blockIdx.y;
    const int t   = threadIdx.x;
    const int w   = t >> 6;
    const int l   = t & 63;
    const int g   = l >> 4;      // k-octet selector
    const int col = l & 15;      // A-row / B-col within 16-tile
    const int ctg = w >> 1;      // c-group (rows 32*ctg ..)
    const int nh  = w & 1;       // n-half

    const float* xb = x + (size_t)b * CHW_;
    const int nq  = nb >> 1;     // n per wave
    const int nw0 = ch * nb + nh * nq;

    f32x4v acc[2][4];            // [ct2][dt]
    #pragma unroll
    for (int ct = 0; ct < 2; ct++)
        #pragma unroll
        for (int dt = 0; dt < 4; dt++) acc[ct][dt] = (f32x4v)(0.f);

    for (int ns = nw0; ns < nw0 + nq; ns += 32) {
        // --- A fragments: lane holds A[32ctg+16ct2+col][ns+8g+j] ---
        bf16x8 ahi[2], alo[2];
        #pragma unroll
        for (int ct = 0; ct < 2; ct++) {
            const float* ap = xb + (size_t)(32 * ctg + 16 * ct + col) * HW_ + ns + 8 * g;
            float av[8];
            *(float4*)&av[0] = *(const float4*)ap;
            *(float4*)&av[4] = *(const float4*)(ap + 4);
            #pragma unroll
            for (int j = 0; j < 8; j++) {
                const unsigned short h = bfrne(av[j]);
                ahi[ct][j] = (short)h;
                alo[ct][j] = (short)bfrne(av[j] - bfdec(h));
            }
        }
        // --- B fragments: lane holds B[ns+8g+j][16dt+col] ---
        bf16x8 bhi[4], blo[4];
        #pragma unroll
        for (int dt = 0; dt < 4; dt++) {
            const float* bp = xb + (size_t)(ns + 8 * g) * C_ + 16 * dt + col;
            float bv[8];
            #pragma unroll
            for (int j = 0; j < 8; j++) bv[j] = bp[j * C_];
            #pragma unroll
            for (int j = 0; j < 8; j++) {
                const unsigned short h = bfrne(bv[j]);
                bhi[dt][j] = (short)h;
                blo[dt][j] = (short)bfrne(bv[j] - bfdec(h));
            }
        }
        // --- 24 MFMAs: hi*hi + hi*lo + lo*hi ---
        #pragma unroll
        for (int ct = 0; ct < 2; ct++)
            #pragma unroll
            for (int dt = 0; dt < 4; dt++) {
                acc[ct][dt] = __builtin_amdgcn_mfma_f32_16x16x32_bf16(
                    ahi[ct], bhi[dt], acc[ct][dt], 0, 0, 0);
                acc[ct][dt] = __builtin_amdgcn_mfma_f32_16x16x32_bf16(
                    ahi[ct], blo[dt], acc[ct][dt], 0, 0, 0);
                acc[ct][dt] = __builtin_amdgcn_mfma_f32_16x16x32_bf16(
                    alo[ct], bhi[dt], acc[ct][dt], 0, 0, 0);
            }
    }

    // --- cross-wave reduce over n-halves ---
    __shared__ float sred[4096];
    for (int wr = 0; wr < 2; wr++) {
        if (nh == wr) {
            #pragma unroll
            for (int ct = 0; ct < 2; ct++)
                #pragma unroll
                for (int dt = 0; dt < 4; dt++)
                    #pragma unroll
                    for (int r = 0; r < 4; r++) {
                        const int idx = (32 * ctg + 16 * ct + 4 * g + r) * 64
                                        + 16 * dt + col;
                        if (wr == 0) sred[idx] = acc[ct][dt][r];
                        else         sred[idx] += acc[ct][dt][r];
                    }
        }
        __syncthreads();
    }

    float* pb = partial + (size_t)(b * nch + ch) * 4096;
    for (int i = 4 * t; i < 4096; i += 1024)
        *(float4*)&pb[i] = *(const float4*)&sred[i];
}

// ---------------------------------------------------------------------------
// Kernel 2 v3: reduce partials + softmax (unchanged).
// Writes mbf[b,c,d] = bf16( softmax(S)[b,c,d] + (c==d) ).
// ---------------------------------------------------------------------------
__global__ __launch_bounds__(256) void k2_softmax(const float* __restrict__ partial,
                                                  unsigned short* __restrict__ mbf,
                                                  int nch) {
    const int c = blockIdx.x;
    const int b = blockIdx.y;
    const int t = threadIdx.x;
    const int w = t >> 6;
    const int d = t & 63;

    float s = 0.f;
    for (int ch = w; ch < nch; ch += 4)
        s += partial[(size_t)(b * nch + ch) * 4096 + c * 64 + d];

    __shared__ float red[256];
    red[t] = s;
    __syncthreads();
    if (w == 0) {
        s = red[d] + red[64 + d] + red[128 + d] + red[192 + d];
        float m = s;
        #pragma unroll
        for (int off = 32; off > 0; off >>= 1) m = fmaxf(m, __shfl_xor(m, off));
        const float e = expf(s - m);
        float sum = e;
        #pragma unroll
        for (int off = 32; off > 0; off >>= 1) sum += __shfl_xor(sum, off);
        mbf[(size_t)b * 4096 + c * 64 + d] = bfrne(e / sum + (c == d ? 1.f : 0.f));
    }
}

// ---------------------------------------------------------------------------
// Kernel 3 v6 (MFMA bf16 — reverted to the proven R8 version; the R10 slim
// variant collapsed its pipeline at VGPR 52 and doubled x traffic):
// out[b,c,n] = sum_d M[c,d] * X[b, d*HW + n]
// ---------------------------------------------------------------------------
__global__ __launch_bounds__(256, 3) void k3_out(const float* __restrict__ x,
                                                 const unsigned short* __restrict__ mbf,
                                                 float* __restrict__ out) {
    const int nbk  = blockIdx.x;
    const int b    = blockIdx.y;
    const int t    = threadIdx.x;
    const int w    = t >> 6;
    const int l    = t & 63;
    const int g    = l >> 4;
    const int col  = l & 15;

    const int n0 = nbk * 256 + w * 64;
    const float* xb = x + (size_t)b * CHW_;

    bf16x8 afr[4][2];
    const unsigned short* mb = mbf + (size_t)b * 4096;
    #pragma unroll
    for (int ct = 0; ct < 4; ct++)
        #pragma unroll
        for (int ks = 0; ks < 2; ks++)
            afr[ct][ks] = *(const bf16x8*)(mb + (16 * ct + col) * 64 + 32 * ks + 8 * g);

    f32x4v acc[4][4];   // [ct][nt]
    #pragma unroll
    for (int ct = 0; ct < 4; ct++)
        #pragma unroll
        for (int nt = 0; nt < 4; nt++)
            acc[ct][nt] = (f32x4v)(0.f);

    #pragma unroll
    for (int nt = 0; nt < 4; nt++) {
        const float* xpf = xb + n0 + 16 * nt + col;
        float xv[2][8];
        #pragma unroll
        for (int ks = 0; ks < 2; ks++)
            #pragma unroll
            for (int j = 0; j < 8; j++)
                xv[ks][j] = xpf[(size_t)(32 * ks + 8 * g + j) * HW_];

        bf16x8 bfr[2];
        #pragma unroll
        for (int ks = 0; ks < 2; ks++)
            #pragma unroll
            for (int j = 0; j < 8; j++)
                bfr[ks][j] = (short)bfrne(xv[ks][j]);

        #pragma unroll
        for (int ct = 0; ct < 4; ct++)
            #pragma unroll
            for (int ks = 0; ks < 2; ks++)
                acc[ct][nt] = __builtin_amdgcn_mfma_f32_16x16x32_bf16(
                    afr[ct][ks], bfr[ks], acc[ct][nt], 0, 0, 0);
    }

    float* ob = out + (size_t)b * CHW_;
    #pragma unroll
    for (int ct = 0; ct < 4; ct++)
        #pragma unroll
        for (int nt = 0; nt < 4; nt++)
            #pragma unroll
            for (int r = 0; r < 4; r++)
                ob[(size_t)(16 * ct + 4 * g + r) * HW_ + n0 + 16 * nt + col] =
                    acc[ct][nt][r];
}

// ---------------------------------------------------------------------------
extern "C" void kernel_launch(void* const* d_in, const int* in_sizes, int n_in,
                              void* d_out, int out_size, void* d_ws, size_t ws_size,
                              hipStream_t stream) {
    const float* x = (const float*)d_in[0];
    float* out = (float*)d_out;

    float* wsf          = (float*)d_ws;
    unsigned short* mbf = (unsigned short*)wsf;      // B*4096 ushorts (128KB)
    float* partial      = wsf + (size_t)B_ * 4096;   // B*nch*4096 floats

    int nch = 64;
    while (nch > 1) {
        size_t need = (size_t)B_ * 4096 * sizeof(float)
                    + (size_t)B_ * nch * 4096 * sizeof(float);
        if (need <= ws_size) break;
        nch >>= 1;
    }
    const int nb = HW_ / nch;

    k1_gram<<<dim3(nch, B_), 256, 0, stream>>>(x, partial, nch, nb);
    k2_softmax<<<dim3(C_, B_), 256, 0, stream>>>(partial, mbf, nch);
    k3_out<<<dim3(HW_ / 256, B_), 256, 0, stream>>>(x, mbf, out);
}